// Round 6
// baseline (770.133 us; speedup 1.0000x reference)
//
#include <hip/hip_runtime.h>
#include <hip/hip_bf16.h>

typedef unsigned short u16;
typedef __bf16 bf16x8 __attribute__((ext_vector_type(8)));
typedef float f32x4 __attribute__((ext_vector_type(4)));

#define LOG2PI_F 1.8378770664093453f

__device__ __forceinline__ u16 f2bf(float f) {
  union { __hip_bfloat16 h; u16 u; } cvt;
  cvt.h = __float2bfloat16(f);
  return cvt.u;
}

__device__ __forceinline__ float fast_tanh(float x) {
  float e = __expf(2.0f * x);
  return 1.0f - 2.0f * __builtin_amdgcn_rcpf(e + 1.0f);
}

__device__ __forceinline__ void load_lds16(const void* g, void* l) {
  __builtin_amdgcn_global_load_lds(
      (const __attribute__((address_space(1))) void*)g,
      (__attribute__((address_space(3))) void*)l,
      16, 0, 0);
}

// ---------------- convert obs f32 -> bf16 ----------------
__global__ void cvt_f32_bf16(const float* __restrict__ in, u16* __restrict__ out, int n4) {
  int i = blockIdx.x * blockDim.x + threadIdx.x;
  int stride = gridDim.x * blockDim.x;
  for (int j = i; j < n4; j += stride) {
    float4 v = reinterpret_cast<const float4*>(in)[j];
    ushort4 o;
    o.x = f2bf(v.x); o.y = f2bf(v.y); o.z = f2bf(v.z); o.w = f2bf(v.w);
    reinterpret_cast<ushort4*>(out)[j] = o;
  }
}

// ------- W [H][K][N] f32 -> Wt [H][N][K] bf16, 64x64 LDS-tiled ---------
__global__ void transpose_cvt(const float* __restrict__ W, u16* __restrict__ Wt,
                              int K, int N) {
  __shared__ u16 t[64][66];
  const int a = blockIdx.z;
  const int n0 = blockIdx.x * 64, k0 = blockIdx.y * 64;
  const float* Wh = W + (size_t)a * K * N;
  u16* Wth = Wt + (size_t)a * N * K;
  const int tid = threadIdx.x;
#pragma unroll
  for (int j = 0; j < 16; ++j) {
    int idx = j * 256 + tid;
    int r = idx >> 6, c = idx & 63;
    t[r][c] = f2bf(Wh[(size_t)(k0 + r) * N + n0 + c]);
  }
  __syncthreads();
#pragma unroll
  for (int j = 0; j < 16; ++j) {
    int idx = j * 256 + tid;
    int r = idx >> 6, c = idx & 63;
    Wth[(size_t)(n0 + r) * K + k0 + c] = t[c][r];
  }
}

// ------- batched-head GEMM, 256x256 tile, BK=64, 8-phase pipeline -------
// 512 thr = 8 waves (2M x 4N), per-wave C = 128x64 (acc[8][4]).
// LDS: [buf=tile&1][op A/B][256x64] bf16 = 128 KiB, double-buffered.
// Schedule per iteration i (tiles T0=2i in buf0, T1=2i+1 in buf1):
//   ph0: ldB(T0,all 8) + ldA(T0,mf01)            | stage --
//   ph1: ldA(T0,mf23)  | stage SA(T1) (buf1-A free since prev ph7)
//   ph2: ldA(T0,mf45)  | stage SB(T2) (buf0-B free after ph0)
//   ph3: ldA(T0,mf67)  | GATE A: vmcnt(4) before closing barrier
//        (certifies SB(T1)@prev-ph5 + SA(T1)@ph1; leaves SB(T2) in flight)
//   ph4: ldB(T1) + ldA(T1,mf01) | stage SA(T2) (buf0-A free after ph3)
//   ph5: ldA(T1,mf23)  | stage SB(T3) (buf1-B free after ph4)
//   ph6: ldA(T1,mf45)
//   ph7: ldA(T1,mf67)  | GATE B: vmcnt(4) (certifies SB(T2),SA(T2);
//        leaves SB(T3) in flight) -> next iter's ph0 reads T2 safely.
// Every phase: reads/stages; s_barrier; setprio(1); 16 MFMA; setprio(0);
// s_barrier. Certification rule: stage is readable only after (every-wave
// vmcnt covering it) + barrier — both gates obey it (verified ledger).
template <int MODE>
__global__ __launch_bounds__(512, 2) void gemm256p(
    const u16* __restrict__ A, long aHeadStride,
    const u16* __restrict__ Bt,
    const float* __restrict__ bias,
    int M, int N, int K, int gridN,
    u16* __restrict__ outBf,
    const float* __restrict__ W3,
    float* __restrict__ muAcc) {
  __shared__ __align__(16) u16 lds[2][2][256 * 64];   // 128 KiB

  const int tid = threadIdx.x;
  const int w = tid >> 6, l = tid & 63;
  const int wm = w >> 2, wn = w & 3;        // 2 (M) x 4 (N) waves
  const int lh = l & 15, lg = l >> 4;

  // T1 technique: bijective XCD swizzle (gridDim.x % 8 == 0)
  const int cpx = gridDim.x >> 3;
  const int bid = (blockIdx.x & 7) * cpx + (blockIdx.x >> 3);
  const int bph = (M >> 8) * gridN;
  const int head = bid / bph;
  const int rem = bid % bph;
  const int m0 = (rem / gridN) << 8;
  const int n0 = (rem % gridN) << 8;

  const u16* Ah = A + (size_t)head * (size_t)aHeadStride;
  const u16* Bh = Bt + (size_t)head * (size_t)N * (size_t)K;

  // stage one half-tile (128 rows x 64 K) of operand op of K-tile T, half h.
  // Linear LDS dest (global_load_lds requirement), pre-swizzled global src
  // slot j^(row&7); read side applies the same XOR (0 conflicts, measured).
  auto stageH = [&](int T, int op, int h) {
    const u16* src = (op == 0) ? Ah : Bh;
    const int base = (op == 0) ? m0 : n0;
    const int kt = T << 6;
    u16* dst = &lds[T & 1][op][h * (128 * 64)];
#pragma unroll
    for (int s = 0; s < 2; ++s) {
      int c = s * 512 + tid;
      int row = c >> 3, j = c & 7;
      int js = j ^ (row & 7);
      load_lds16(src + (size_t)(base + h * 128 + row) * K + kt + js * 8,
                 dst + c * 8);
    }
  };

  f32x4 acc[8][4] = {};
  bf16x8 bq[4][2];                 // current tile's B fragments (kept in regs)
  const u16* const As0 = lds[0][0];
  const u16* const Bs0 = lds[0][1];
  const u16* const As1 = lds[1][0];
  const u16* const Bs1 = lds[1][1];
  const int NT = K >> 6;

#define LDB(Bs)                                                              \
  _Pragma("unroll")                                                          \
  for (int nf = 0; nf < 4; ++nf)                                             \
    _Pragma("unroll")                                                        \
    for (int ks = 0; ks < 2; ++ks) {                                         \
      const int row = wn * 64 + nf * 16 + lh;                                \
      const int j = (ks * 4 + lg) ^ (lh & 7);                                \
      bq[nf][ks] = *reinterpret_cast<const bf16x8*>(&(Bs)[row * 64 + j * 8]); \
    }

#define LDA(As, P, af)                                                       \
  _Pragma("unroll")                                                          \
  for (int q = 0; q < 2; ++q)                                                \
    _Pragma("unroll")                                                        \
    for (int ks = 0; ks < 2; ++ks) {                                         \
      const int row = wm * 128 + (2 * (P) + q) * 16 + lh;                    \
      const int j = (ks * 4 + lg) ^ (lh & 7);                                \
      af[q][ks] = *reinterpret_cast<const bf16x8*>(&(As)[row * 64 + j * 8]); \
    }

#define MFMA16(P, af)                                                        \
  __builtin_amdgcn_s_setprio(1);                                             \
  _Pragma("unroll")                                                          \
  for (int ks = 0; ks < 2; ++ks)                                             \
    _Pragma("unroll")                                                        \
    for (int q = 0; q < 2; ++q)                                              \
      _Pragma("unroll")                                                      \
      for (int nf = 0; nf < 4; ++nf)                                         \
        acc[2 * (P) + q][nf] = __builtin_amdgcn_mfma_f32_16x16x32_bf16(      \
            af[q][ks], bq[nf][ks], acc[2 * (P) + q][nf], 0, 0, 0);           \
  __builtin_amdgcn_s_setprio(0);

  // prologue: B(0), A(0) [8 loads], B(1) [4 loads]; vmcnt(4) drains tile 0,
  // leaves SB(1) in flight (certified later by Gate A of iter 0).
  stageH(0, 1, 0); stageH(0, 1, 1);
  stageH(0, 0, 0); stageH(0, 0, 1);
  stageH(1, 1, 0); stageH(1, 1, 1);
  asm volatile("s_waitcnt vmcnt(4)" ::: "memory");
  __builtin_amdgcn_sched_barrier(0);
  __builtin_amdgcn_s_barrier();

  for (int i = 0; i < NT / 2; ++i) {
    const int t0 = 2 * i;
    const bool pref = (t0 + 2) < NT;

    { // ph0
      bf16x8 af[2][2];
      LDB(Bs0);
      LDA(As0, 0, af);
      __builtin_amdgcn_s_barrier();
      MFMA16(0, af);
      __builtin_amdgcn_s_barrier();
    }
    { // ph1
      bf16x8 af[2][2];
      LDA(As0, 1, af);
      stageH(t0 + 1, 0, 0); stageH(t0 + 1, 0, 1);
      __builtin_amdgcn_s_barrier();
      MFMA16(1, af);
      __builtin_amdgcn_s_barrier();
    }
    { // ph2
      bf16x8 af[2][2];
      LDA(As0, 2, af);
      if (pref) { stageH(t0 + 2, 1, 0); stageH(t0 + 2, 1, 1); }
      __builtin_amdgcn_s_barrier();
      MFMA16(2, af);
      __builtin_amdgcn_s_barrier();
    }
    { // ph3 + Gate A
      bf16x8 af[2][2];
      LDA(As0, 3, af);
      __builtin_amdgcn_s_barrier();
      MFMA16(3, af);
      if (pref) asm volatile("s_waitcnt vmcnt(4)" ::: "memory");
      else      asm volatile("s_waitcnt vmcnt(0)" ::: "memory");
      __builtin_amdgcn_sched_barrier(0);
      __builtin_amdgcn_s_barrier();
    }
    { // ph4
      bf16x8 af[2][2];
      LDB(Bs1);
      LDA(As1, 0, af);
      if (pref) { stageH(t0 + 2, 0, 0); stageH(t0 + 2, 0, 1); }
      __builtin_amdgcn_s_barrier();
      MFMA16(0, af);
      __builtin_amdgcn_s_barrier();
    }
    { // ph5
      bf16x8 af[2][2];
      LDA(As1, 1, af);
      if (pref) { stageH(t0 + 3, 1, 0); stageH(t0 + 3, 1, 1); }
      __builtin_amdgcn_s_barrier();
      MFMA16(1, af);
      __builtin_amdgcn_s_barrier();
    }
    { // ph6
      bf16x8 af[2][2];
      LDA(As1, 2, af);
      __builtin_amdgcn_s_barrier();
      MFMA16(2, af);
      __builtin_amdgcn_s_barrier();
    }
    { // ph7 + Gate B
      bf16x8 af[2][2];
      LDA(As1, 3, af);
      __builtin_amdgcn_s_barrier();
      MFMA16(3, af);
      if (pref) {
        asm volatile("s_waitcnt vmcnt(4)" ::: "memory");
        __builtin_amdgcn_sched_barrier(0);
      }
      __builtin_amdgcn_s_barrier();
    }
  }

#undef LDB
#undef LDA
#undef MFMA16

  if (MODE == 1) {
    u16* Oh = outBf + (size_t)head * (size_t)M * (size_t)N;
#pragma unroll
    for (int mf = 0; mf < 8; ++mf) {
#pragma unroll
      for (int r = 0; r < 4; ++r) {
        const int row = m0 + wm * 128 + mf * 16 + lg * 4 + r;
#pragma unroll
        for (int nf = 0; nf < 4; ++nf) {
          const int col = n0 + wn * 64 + nf * 16 + lh;
          float v = acc[mf][nf][r] + bias[head * N + col];
          Oh[(size_t)row * N + col] = f2bf(fast_tanh(v));
        }
      }
    }
  } else {
#pragma unroll
    for (int mf = 0; mf < 8; ++mf) {
#pragma unroll
      for (int r = 0; r < 4; ++r) {
        const int row = m0 + wm * 128 + mf * 16 + lg * 4 + r;
        float p = 0.f;
#pragma unroll
        for (int nf = 0; nf < 4; ++nf) {
          const int col = n0 + wn * 64 + nf * 16 + lh;
          float v = acc[mf][nf][r] + bias[head * N + col];
          p += fast_tanh(v) * W3[head * N + col];
        }
        p += __shfl_xor(p, 1);
        p += __shfl_xor(p, 2);
        p += __shfl_xor(p, 4);
        p += __shfl_xor(p, 8);
        if (lh == 0) atomicAdd(&muAcc[(size_t)row * 32 + head], p);
      }
    }
  }
}

// ------------- finalize: mu = acc + b3; logp reduction -------------
__global__ void finalize_kernel(const float* __restrict__ muAcc,
                                const float* __restrict__ b3,
                                const float* __restrict__ lstd,
                                const float* __restrict__ act,
                                float* __restrict__ out, int M) {
  int b = blockIdx.x * 256 + threadIdx.x;
  if (b >= M) return;
  float lp = 0.f;
#pragma unroll
  for (int a = 0; a < 32; ++a) {
    float mu = muAcc[(size_t)b * 32 + a] + b3[a];
    out[(size_t)b * 32 + a] = mu;
    float ls = lstd[a];
    float z = (act[(size_t)b * 32 + a] - mu) * __expf(-ls);
    lp += -0.5f * (z * z + LOG2PI_F) - ls;
  }
  out[(size_t)M * 32 + b] = lp;
}

extern "C" void kernel_launch(void* const* d_in, const int* in_sizes, int n_in,
                              void* d_out, int out_size, void* d_ws, size_t ws_size,
                              hipStream_t stream) {
  const float* obs = (const float*)d_in[0];
  const float* act = (const float*)d_in[1];
  const float* W1 = (const float*)d_in[2];
  const float* b1 = (const float*)d_in[3];
  const float* W2 = (const float*)d_in[4];
  const float* b2 = (const float*)d_in[5];
  const float* W3 = (const float*)d_in[6];
  const float* b3 = (const float*)d_in[7];
  const float* lstd = (const float*)d_in[8];

  constexpr int B = 4096, OBS = 512, A = 32, H1 = 1024, H2 = 1024;

  u16* obs_bf = (u16*)d_ws;                              // [B][OBS]
  u16* W1t = obs_bf + (size_t)B * OBS;                   // [A][H1][OBS]
  u16* W2t = W1t + (size_t)A * H1 * OBS;                 // [A][H2][H1]
  u16* x1 = W2t + (size_t)A * H2 * H1;                   // [A][B][H1]
  float* muAcc = (float*)(x1 + (size_t)A * B * H1);      // [B][A]
  float* out = (float*)d_out;

  hipMemsetAsync(muAcc, 0, (size_t)B * A * sizeof(float), stream);

  cvt_f32_bf16<<<1024, 256, 0, stream>>>(obs, obs_bf, B * OBS / 4);
  transpose_cvt<<<dim3(H1 / 64, OBS / 64, A), 256, 0, stream>>>(W1, W1t, OBS, H1);
  transpose_cvt<<<dim3(H2 / 64, H1 / 64, A), 256, 0, stream>>>(W2, W2t, H1, H2);

  // 2048 blocks each (divisible by 8 for the XCD swizzle)
  gemm256p<1><<<(B / 256) * (H1 / 256) * A, 512, 0, stream>>>(
      obs_bf, 0L, W1t, b1, B, H1, OBS, H1 / 256, x1, nullptr, nullptr);

  gemm256p<2><<<(B / 256) * (H2 / 256) * A, 512, 0, stream>>>(
      x1, (long)B * H1, W2t, b2, B, H2, H1, H2 / 256, nullptr, W3, muAcc);

  finalize_kernel<<<B / 256, 256, 0, stream>>>(muAcc, b3, lstd, act, out, B);
}

// Round 8
// 755.031 us; speedup vs baseline: 1.0200x; 1.0200x over previous
//
#include <hip/hip_runtime.h>
#include <hip/hip_bf16.h>

typedef unsigned short u16;
typedef unsigned int u32;
typedef __bf16 bf16x8 __attribute__((ext_vector_type(8)));
typedef u16 u16x8 __attribute__((ext_vector_type(8)));
typedef float f32x4 __attribute__((ext_vector_type(4)));

#define LOG2PI_F 1.8378770664093453f

__device__ __forceinline__ u16 f2bf(float f) {
  union { __hip_bfloat16 h; u16 u; } cvt;
  cvt.h = __float2bfloat16(f);
  return cvt.u;
}

__device__ __forceinline__ float fast_tanh(float x) {
  float e = __expf(2.0f * x);
  return 1.0f - 2.0f * __builtin_amdgcn_rcpf(e + 1.0f);
}

__device__ __forceinline__ void load_lds16(const void* g, void* l) {
  __builtin_amdgcn_global_load_lds(
      (const __attribute__((address_space(1))) void*)g,
      (__attribute__((address_space(3))) void*)l,
      16, 0, 0);
}

// ---------------- convert obs f32 -> bf16 ----------------
__global__ void cvt_f32_bf16(const float* __restrict__ in, u16* __restrict__ out, int n4) {
  int i = blockIdx.x * blockDim.x + threadIdx.x;
  int stride = gridDim.x * blockDim.x;
  for (int j = i; j < n4; j += stride) {
    float4 v = reinterpret_cast<const float4*>(in)[j];
    ushort4 o;
    o.x = f2bf(v.x); o.y = f2bf(v.y); o.z = f2bf(v.z); o.w = f2bf(v.w);
    reinterpret_cast<ushort4*>(out)[j] = o;
  }
}

// ---- W [A][K][N] f32 -> Wt [A][N][K] bf16, vectorized both sides ----
// Load: thread reads 8 consecutive n (2x float4, 32B). Store: thread writes
// 8 consecutive k as one 16B u16x8 (128B per 8 lanes). LDS pad 70 u16
// (140B rows): column reads spread banks -> <=2-way (free).
__global__ void transpose_cvt(const float* __restrict__ W, u16* __restrict__ Wt,
                              int K, int N) {
  __shared__ u16 t[64][70];
  const int a = blockIdx.z;
  const int n0 = blockIdx.x * 64, k0 = blockIdx.y * 64;
  const float* Wh = W + (size_t)a * K * N;
  u16* Wth = Wt + (size_t)a * N * K;
  const int tid = threadIdx.x;

  const int kk = tid >> 3, nn = (tid & 7) * 8;
#pragma unroll
  for (int p = 0; p < 2; ++p) {
    const int k = kk + p * 32;
    const float4* src =
        reinterpret_cast<const float4*>(&Wh[(size_t)(k0 + k) * N + n0 + nn]);
    float4 v0 = src[0];
    float4 v1 = src[1];
    u32* dst = reinterpret_cast<u32*>(&t[k][nn]);
    dst[0] = (u32)f2bf(v0.x) | ((u32)f2bf(v0.y) << 16);
    dst[1] = (u32)f2bf(v0.z) | ((u32)f2bf(v0.w) << 16);
    dst[2] = (u32)f2bf(v1.x) | ((u32)f2bf(v1.y) << 16);
    dst[3] = (u32)f2bf(v1.z) | ((u32)f2bf(v1.w) << 16);
  }
  __syncthreads();

  const int kk8 = (tid & 7) * 8;
#pragma unroll
  for (int p = 0; p < 2; ++p) {
    const int n = (tid >> 3) + p * 32;
    u16x8 v;
#pragma unroll
    for (int q = 0; q < 8; ++q) v[q] = t[kk8 + q][n];
    *reinterpret_cast<u16x8*>(&Wth[(size_t)(n0 + n) * K + k0 + kk8]) = v;
  }
}

// ---- batched-head GEMM, 256x256 tile, BK=64, 16 waves, dbuf+counted vmcnt --
// 1024 thr = 16 waves (4m x 4n), per-wave 64x64 C (acc[4][4], 64 regs) ->
// VGPR ~115 fits 4 waves/SIMD. LDS 128 KiB dbuf -> 1 block/CU, but 16
// resident waves drive the staging path (staging-BW model, round 6 PM).
// Both-sides XOR swizzle (0 conflicts, measured r3/r5/r6). Counted-vmcnt
// double-buffer identical to round-3's verified ledger.
// MODE 1: outBf[h][M][N] = bf16(tanh(A@B + bias))
// MODE 2: atomicAdd muAcc[row][h] += sum_col tanh(A@B+bias)*W3[h][col]
template <int MODE>
__global__ __launch_bounds__(1024, 4) void gemm256(
    const u16* __restrict__ A, long aHeadStride,
    const u16* __restrict__ Bt,
    const float* __restrict__ bias,
    int M, int N, int K, int gridN,
    u16* __restrict__ outBf,
    const float* __restrict__ W3,
    float* __restrict__ muAcc) {
  __shared__ __align__(16) u16 lds[2][2][256 * 64];   // 128 KiB

  const int tid = threadIdx.x;
  const int w = tid >> 6, l = tid & 63;
  const int wm = w >> 2, wn = w & 3;        // 4x4 waves, 64x64 each
  const int lh = l & 15, lg = l >> 4;

  // bijective XCD swizzle (gridDim.x % 8 == 0 by construction)
  const int cpx = gridDim.x >> 3;
  const int bid = (blockIdx.x & 7) * cpx + (blockIdx.x >> 3);
  const int bph = (M >> 8) * gridN;
  const int head = bid / bph;
  const int rem = bid % bph;
  const int m0 = (rem / gridN) << 8;        // n-minor: A panel reused by
  const int n0 = (rem % gridN) << 8;        // consecutive bids on same XCD

  const u16* Ah = A + (size_t)head * (size_t)aHeadStride;
  const u16* Bh = Bt + (size_t)head * (size_t)N * (size_t)K;

  // stage both 256x64 operand tiles: linear LDS dest, pre-swizzled global
  // source slot j^(row&7); 4 loads/thread.
  auto stage = [&](int buf, int kt) {
#pragma unroll
    for (int i = 0; i < 2; ++i) {
      int c = i * 1024 + tid;
      int row = c >> 3, j = c & 7;
      int js = j ^ (row & 7);
      load_lds16(Ah + (size_t)(m0 + row) * K + kt + js * 8, &lds[buf][0][c * 8]);
    }
#pragma unroll
    for (int i = 0; i < 2; ++i) {
      int c = i * 1024 + tid;
      int row = c >> 3, j = c & 7;
      int js = j ^ (row & 7);
      load_lds16(Bh + (size_t)(n0 + row) * K + kt + js * 8, &lds[buf][1][c * 8]);
    }
  };

  f32x4 acc[4][4] = {};
  const int NT = K >> 6;

  // prologue: tiles 0,1 in flight (8 loads); drain tile 0 (4 stay in flight)
  stage(0, 0);
  stage(1, 64);
  asm volatile("s_waitcnt vmcnt(4)" ::: "memory");
  __builtin_amdgcn_sched_barrier(0);
  __builtin_amdgcn_s_barrier();

  for (int t = 0; t < NT; ++t) {
    const u16* As = lds[t & 1][0];
    const u16* Bs = lds[t & 1][1];

#pragma unroll
    for (int ks = 0; ks < 2; ++ks) {
      bf16x8 af[4], bfr[4];
#pragma unroll
      for (int nf = 0; nf < 4; ++nf) {
        const int row = wn * 64 + nf * 16 + lh;
        const int j = (ks * 4 + lg) ^ (lh & 7);
        bfr[nf] = *reinterpret_cast<const bf16x8*>(&Bs[row * 64 + j * 8]);
      }
#pragma unroll
      for (int mf = 0; mf < 4; ++mf) {
        const int row = wm * 64 + mf * 16 + lh;
        const int j = (ks * 4 + lg) ^ (lh & 7);
        af[mf] = *reinterpret_cast<const bf16x8*>(&As[row * 64 + j * 8]);
      }
#pragma unroll
      for (int mf = 0; mf < 4; ++mf)
#pragma unroll
        for (int nf = 0; nf < 4; ++nf)
          acc[mf][nf] = __builtin_amdgcn_mfma_f32_16x16x32_bf16(
              af[mf], bfr[nf], acc[mf][nf], 0, 0, 0);
    }

    // barrier 1: all waves done reading buf[t&1] -> safe to overwrite
    __builtin_amdgcn_s_barrier();
    __builtin_amdgcn_sched_barrier(0);
    if (t + 2 < NT) {
      stage(t & 1, (t + 2) << 6);
      asm volatile("s_waitcnt vmcnt(4)" ::: "memory");  // drain t+1, keep t+2
    } else {
      asm volatile("s_waitcnt vmcnt(0)" ::: "memory");
    }
    __builtin_amdgcn_sched_barrier(0);
    // barrier 2: tile t+1 certified visible to all waves
    __builtin_amdgcn_s_barrier();
  }

  if (MODE == 1) {
    u16* Oh = outBf + (size_t)head * (size_t)M * (size_t)N;
#pragma unroll
    for (int mf = 0; mf < 4; ++mf) {
#pragma unroll
      for (int r = 0; r < 4; ++r) {
        const int row = m0 + wm * 64 + mf * 16 + lg * 4 + r;
#pragma unroll
        for (int nf = 0; nf < 4; ++nf) {
          const int col = n0 + wn * 64 + nf * 16 + lh;
          float v = acc[mf][nf][r] + bias[head * N + col];
          Oh[(size_t)row * N + col] = f2bf(fast_tanh(v));
        }
      }
    }
  } else {
#pragma unroll
    for (int mf = 0; mf < 4; ++mf) {
#pragma unroll
      for (int r = 0; r < 4; ++r) {
        const int row = m0 + wm * 64 + mf * 16 + lg * 4 + r;
        float p = 0.f;
#pragma unroll
        for (int nf = 0; nf < 4; ++nf) {
          const int col = n0 + wn * 64 + nf * 16 + lh;
          float v = acc[mf][nf][r] + bias[head * N + col];
          p += fast_tanh(v) * W3[head * N + col];
        }
        p += __shfl_xor(p, 1);
        p += __shfl_xor(p, 2);
        p += __shfl_xor(p, 4);
        p += __shfl_xor(p, 8);
        if (lh == 0) atomicAdd(&muAcc[(size_t)row * 32 + head], p);
      }
    }
  }
}

// ------------- finalize: mu = acc + b3; logp reduction -------------
__global__ void finalize_kernel(const float* __restrict__ muAcc,
                                const float* __restrict__ b3,
                                const float* __restrict__ lstd,
                                const float* __restrict__ act,
                                float* __restrict__ out, int M) {
  int b = blockIdx.x * 256 + threadIdx.x;
  if (b >= M) return;
  float lp = 0.f;
#pragma unroll
  for (int a = 0; a < 32; ++a) {
    float mu = muAcc[(size_t)b * 32 + a] + b3[a];
    out[(size_t)b * 32 + a] = mu;
    float ls = lstd[a];
    float z = (act[(size_t)b * 32 + a] - mu) * __expf(-ls);
    lp += -0.5f * (z * z + LOG2PI_F) - ls;
  }
  out[(size_t)M * 32 + b] = lp;
}

extern "C" void kernel_launch(void* const* d_in, const int* in_sizes, int n_in,
                              void* d_out, int out_size, void* d_ws, size_t ws_size,
                              hipStream_t stream) {
  const float* obs = (const float*)d_in[0];
  const float* act = (const float*)d_in[1];
  const float* W1 = (const float*)d_in[2];
  const float* b1 = (const float*)d_in[3];
  const float* W2 = (const float*)d_in[4];
  const float* b2 = (const float*)d_in[5];
  const float* W3 = (const float*)d_in[6];
  const float* b3 = (const float*)d_in[7];
  const float* lstd = (const float*)d_in[8];

  constexpr int B = 4096, OBS = 512, A = 32, H1 = 1024, H2 = 1024;

  u16* obs_bf = (u16*)d_ws;                              // [B][OBS]
  u16* W1t = obs_bf + (size_t)B * OBS;                   // [A][H1][OBS]
  u16* W2t = W1t + (size_t)A * H1 * OBS;                 // [A][H2][H1]
  u16* x1 = W2t + (size_t)A * H2 * H1;                   // [A][B][H1]
  float* muAcc = (float*)(x1 + (size_t)A * B * H1);      // [B][A]
  float* out = (float*)d_out;

  hipMemsetAsync(muAcc, 0, (size_t)B * A * sizeof(float), stream);

  cvt_f32_bf16<<<1024, 256, 0, stream>>>(obs, obs_bf, B * OBS / 4);
  transpose_cvt<<<dim3(H1 / 64, OBS / 64, A), 256, 0, stream>>>(W1, W1t, OBS, H1);
  transpose_cvt<<<dim3(H2 / 64, H1 / 64, A), 256, 0, stream>>>(W2, W2t, H1, H2);

  // 2048 blocks each (divisible by 8 for the XCD swizzle)
  gemm256<1><<<(B / 256) * (H1 / 256) * A, 1024, 0, stream>>>(
      obs_bf, 0L, W1t, b1, B, H1, OBS, H1 / 256, x1, nullptr, nullptr);

  gemm256<2><<<(B / 256) * (H2 / 256) * A, 1024, 0, stream>>>(
      x1, (long)B * H1, W2t, b2, B, H2, H1, H2 / 256, nullptr, W3, muAcc);

  finalize_kernel<<<B / 256, 256, 0, stream>>>(muAcc, b3, lstd, act, out, B);
}